// Round 1
// baseline (146.731 us; speedup 1.0000x reference)
//
#include <hip/hip_runtime.h>

// GNNCriticEncoder fused kernel (MI355X / gfx950)
// B=4096 items; per item: embed(16x40->128,16x24->128) -> 2x GAT(E=128,H=4,DH=32) -> masked mean pool.
// One wave (64 lanes) per batch item, 4 items per 256-thread block, bf16 MFMA 16x16x32 throughout.

#define NTOK 32
#define EMB  128
#define NH   4
#define OBSL 1056
#define XSTR 136   // s_xh row stride in bf16: 272B = 17*16B -> aligned b128, conflict-friendly
#define WSTR 72    // s_w  row stride in bf16: 144B = 9*16B

typedef __attribute__((ext_vector_type(8))) short  short8;   // 8 x bf16 (4 VGPRs) MFMA A/B frag
typedef __attribute__((ext_vector_type(4))) float  floatx4;  // MFMA C/D frag

__device__ __forceinline__ short f2bf(float f) {
  union { float f; unsigned u; } v; v.f = f;
  unsigned r = (v.u + 0x7fffu + ((v.u >> 16) & 1u)) >> 16;  // RNE fp32->bf16
  return (short)(unsigned short)r;
}
__device__ __forceinline__ float elu1(float v) { return v > 0.f ? v : __expf(v) - 1.f; }

__device__ __forceinline__ floatx4 mfma16(short8 a, short8 b, floatx4 c) {
  return __builtin_amdgcn_mfma_f32_16x16x32_bf16(a, b, c, 0, 0, 0);
}

// Stage one K-half (64 rows) of w (global [k][e], row-major 128x128 fp32) into s_w[e][k_local] bf16.
__device__ __forceinline__ void stage_w_half(short* sw, const float* gw, int half, int tid) {
  const int e   = tid & 127;
  const int kk0 = (tid >> 7) * 32;
  const float* src = gw + (size_t)(half * 64 + kk0) * EMB + e;  // coalesced over e
  #pragma unroll
  for (int kk = 0; kk < 32; kk += 2) {
    float v0 = src[(size_t)kk * EMB];
    float v1 = src[(size_t)(kk + 1) * EMB];
    unsigned pk = (unsigned)(unsigned short)f2bf(v0) | ((unsigned)(unsigned short)f2bf(v1) << 16);
    *(unsigned*)&sw[e * WSTR + kk0 + kk] = pk;
  }
}

__global__ __launch_bounds__(256, 2) void gnn_fused(
    const float* __restrict__ obs,
    const float* __restrict__ Wv, const float* __restrict__ bv,
    const float* __restrict__ Wp, const float* __restrict__ bp,
    const float* __restrict__ w0, const float* __restrict__ as0, const float* __restrict__ ad0,
    const float* __restrict__ w1, const float* __restrict__ as1, const float* __restrict__ ad1,
    float* __restrict__ out)
{
  __shared__ __align__(16) short s_w[EMB * WSTR];       // 18432 B: embT / w half (K-split)
  __shared__ __align__(16) short s_xh[EMB * XSTR];      // 34816 B: x[token][e] <-> hT[e][token]
  __shared__ __align__(16) float s_alpha[2 * NH * 128]; // 4096 B: [src|dst][hh][token]; reused for pool
  __shared__ __align__(16) float s_alive[128];          // per item 32 flags
  __shared__ float s_inv[4];                            // 1/count per item

  const int tid  = threadIdx.x;
  const int lane = tid & 63;
  const int wv   = tid >> 6;       // wave id = item within block
  const int col  = lane & 15;      // MFMA m/n lane index
  const int quad = lane >> 4;      // MFMA k-chunk / C-row group
  const int b    = blockIdx.x * 4 + wv;

  const float* orow = obs + (size_t)b * OBSL;
  short* xbase = &s_xh[(wv * NTOK) * XSTR];
  const short8  z8 = {0,0,0,0,0,0,0,0};
  const floatx4 fz = {0.f,0.f,0.f,0.f};

  // ---------------- P0: build xin (zero-pad K=64), alive flags, stage embT ----------------
  #pragma unroll
  for (int it = 0; it < 4; ++it) {                       // zero cols [0,64) of own 32 rows
    int c = it * 64 + lane;                              // 256 chunks of 8 bf16
    *(short8*)&xbase[(c >> 3) * XSTR + (c & 7) * 8] = z8;
  }
  {
    float araw = (lane < NTOK) ? orow[1024 + lane] : 0.f;
    bool alv = (lane < NTOK) && (araw >= 0.5f);
    unsigned long long m = __ballot(alv);
    int cnt = __popcll(m);
    float flag = alv ? 1.f : 0.f;
    if (cnt == 0) { flag = (lane < NTOK) ? 1.f : 0.f; cnt = NTOK; }  // all-dead -> all alive
    if (lane < NTOK) s_alive[wv * NTOK + lane] = flag;
    if (lane == 0) s_inv[wv] = 1.f / (float)cnt;
  }
  for (int idx = lane; idx < 1024; idx += 64) {          // coalesced read, bf16 scatter
    float v = orow[idx];
    int r, k;
    if (idx < 640) { r = idx / 40; k = idx % 40; }                       // veh: k in [0,40)
    else { int t2 = idx - 640; r = 16 + t2 / 24; k = 40 + t2 % 24; }     // ped: k in [40,64)
    xbase[r * XSTR + k] = f2bf(v);
  }
  {
    // embT = [Wv;Wp] transposed: s_w[e][k], k<64 (rows 0..39 Wv, 40..63 Wp)
    const int e = tid & 127;
    const int k0 = (tid >> 7) * 32;
    #pragma unroll
    for (int kk = 0; kk < 32; kk += 2) {
      int k = k0 + kk;
      float v0 = (k < 40) ? Wv[(size_t)k * EMB + e] : Wp[(size_t)(k - 40) * EMB + e];
      float v1 = (k + 1 < 40) ? Wv[(size_t)(k + 1) * EMB + e] : Wp[(size_t)(k + 1 - 40) * EMB + e];
      unsigned pk = (unsigned)(unsigned short)f2bf(v0) | ((unsigned)(unsigned short)f2bf(v1) << 16);
      *(unsigned*)&s_w[e * WSTR + k] = pk;
    }
  }
  __syncthreads();

  // ---------------- P1: embed  x[token][e] = xin @ Wcat + bias ----------------
  {
    short8 Aem[2][2];                                    // all A-frags BEFORE overwriting rows
    #pragma unroll
    for (int mtT = 0; mtT < 2; ++mtT)
      #pragma unroll
      for (int kt = 0; kt < 2; ++kt)
        Aem[mtT][kt] = *(const short8*)&s_xh[(wv * NTOK + mtT * 16 + col) * XSTR + kt * 32 + quad * 8];
    #pragma unroll
    for (int nt = 0; nt < 8; ++nt) {
      short8 B0 = *(const short8*)&s_w[(nt * 16 + col) * WSTR + quad * 8];
      short8 B1 = *(const short8*)&s_w[(nt * 16 + col) * WSTR + 32 + quad * 8];
      float bvv = bv[nt * 16 + col];
      float bpv = bp[nt * 16 + col];
      #pragma unroll
      for (int mtT = 0; mtT < 2; ++mtT) {
        floatx4 acc = fz;
        acc = mfma16(Aem[mtT][0], B0, acc);
        acc = mfma16(Aem[mtT][1], B1, acc);
        float bias = mtT ? bpv : bvv;
        #pragma unroll
        for (int r = 0; r < 4; ++r)
          s_xh[(wv * NTOK + mtT * 16 + quad * 4 + r) * XSTR + nt * 16 + col] = f2bf(acc[r] + bias);
      }
    }
  }

  const float* const gws[2] = {w0, w1};
  const float* const gass[2] = {as0, as1};
  const float* const gads[2] = {ad0, ad1};

  for (int L = 0; L < 2; ++L) {
    const float* gw  = gws[L];
    const float* gas = gass[L];
    const float* gad = gads[L];

    // ---- load ALL x B-frags (own strip) into regs, then x buffer may become hT ----
    short8 Bx[4][2];  // [k-tile 0..3][token-tile 0..1]
    #pragma unroll
    for (int kB = 0; kB < 4; ++kB)
      #pragma unroll
      for (int nt = 0; nt < 2; ++nt)
        Bx[kB][nt] = *(const short8*)&s_xh[(wv * NTOK + nt * 16 + col) * XSTR + kB * 32 + quad * 8];
    __syncthreads();                       // everyone done reading x; s_w free
    stage_w_half(s_w, gw, 0, tid);
    __syncthreads();

    // ---- hT[e][token] = w^T x^T : M=128(e) x N=32(tok) x K=128, K-split in 2 halves ----
    floatx4 acc[8][2];
    #pragma unroll
    for (int mt = 0; mt < 8; ++mt) { acc[mt][0] = fz; acc[mt][1] = fz; }
    #pragma unroll
    for (int mt = 0; mt < 8; ++mt) {
      short8 A0 = *(const short8*)&s_w[(mt * 16 + col) * WSTR + quad * 8];
      short8 A1 = *(const short8*)&s_w[(mt * 16 + col) * WSTR + 32 + quad * 8];
      #pragma unroll
      for (int nt = 0; nt < 2; ++nt) {
        acc[mt][nt] = mfma16(A0, Bx[0][nt], acc[mt][nt]);
        acc[mt][nt] = mfma16(A1, Bx[1][nt], acc[mt][nt]);
      }
    }
    __syncthreads();
    stage_w_half(s_w, gw, 1, tid);
    __syncthreads();
    #pragma unroll
    for (int mt = 0; mt < 8; ++mt) {
      short8 A0 = *(const short8*)&s_w[(mt * 16 + col) * WSTR + quad * 8];
      short8 A1 = *(const short8*)&s_w[(mt * 16 + col) * WSTR + 32 + quad * 8];
      #pragma unroll
      for (int nt = 0; nt < 2; ++nt) {
        acc[mt][nt] = mfma16(A0, Bx[2][nt], acc[mt][nt]);
        acc[mt][nt] = mfma16(A1, Bx[3][nt], acc[mt][nt]);
      }
    }

    // ---- alpha from fp32 C-regs + hT -> LDS (bf16) ----
    float psrc[NH][2], pdst[NH][2];
    #pragma unroll
    for (int hh = 0; hh < NH; ++hh) { psrc[hh][0]=0.f; psrc[hh][1]=0.f; pdst[hh][0]=0.f; pdst[hh][1]=0.f; }
    #pragma unroll
    for (int mt = 0; mt < 8; ++mt) {
      const int hh = mt >> 1;
      float4 cs = *(const float4*)&gas[mt * 16 + quad * 4];  // asrc[e], e = mt*16+quad*4+r
      float4 cd = *(const float4*)&gad[mt * 16 + quad * 4];
      #pragma unroll
      for (int nt = 0; nt < 2; ++nt) {
        floatx4 a = acc[mt][nt];
        psrc[hh][nt] += a[0]*cs.x + a[1]*cs.y + a[2]*cs.z + a[3]*cs.w;
        pdst[hh][nt] += a[0]*cd.x + a[1]*cd.y + a[2]*cd.z + a[3]*cd.w;
        #pragma unroll
        for (int r = 0; r < 4; ++r)
          s_xh[(mt * 16 + quad * 4 + r) * XSTR + wv * NTOK + nt * 16 + col] = f2bf(a[r]);
      }
    }
    #pragma unroll
    for (int hh = 0; hh < NH; ++hh)
      #pragma unroll
      for (int nt = 0; nt < 2; ++nt) {
        float vs = psrc[hh][nt], vd = pdst[hh][nt];
        vs += __shfl_xor(vs, 16); vs += __shfl_xor(vs, 32);   // sum the 4 quads (full 32-ch head)
        vd += __shfl_xor(vd, 16); vd += __shfl_xor(vd, 32);
        if (quad == 0) {
          s_alpha[hh * 128 + wv * NTOK + nt * 16 + col] = vs;
          s_alpha[512 + hh * 128 + wv * NTOK + nt * 16 + col] = vd;
        }
      }

    // ---- softmax directly in PV B-frag layout: lane owns (i = ii*16+col, j = quad*8..+7) ----
    float alv8[8];
    #pragma unroll
    for (int j = 0; j < 8; ++j) alv8[j] = s_alive[wv * NTOK + quad * 8 + j];
    short8 pfrag[NH][2];
    #pragma unroll
    for (int hh = 0; hh < NH; ++hh) {
      float ad8[8];
      #pragma unroll
      for (int j = 0; j < 8; ++j) ad8[j] = s_alpha[512 + hh * 128 + wv * NTOK + quad * 8 + j];
      #pragma unroll
      for (int ii = 0; ii < 2; ++ii) {
        float ai = s_alpha[hh * 128 + wv * NTOK + ii * 16 + col];
        float ev[8]; float mx = -1e30f;
        #pragma unroll
        for (int j = 0; j < 8; ++j) {
          float e = ai + ad8[j];
          e = e > 0.f ? e : 0.2f * e;                    // leaky relu, then key mask
          e = (alv8[j] >= 0.5f) ? e : -1e30f;
          ev[j] = e; mx = fmaxf(mx, e);
        }
        mx = fmaxf(mx, __shfl_xor(mx, 16));
        mx = fmaxf(mx, __shfl_xor(mx, 32));
        float sum = 0.f;
        #pragma unroll
        for (int j = 0; j < 8; ++j) { float p = __expf(ev[j] - mx); ev[j] = p; sum += p; }
        sum += __shfl_xor(sum, 16);
        sum += __shfl_xor(sum, 32);
        float inv = 1.f / sum;                            // >=1 alive key guaranteed
        short8 pf;
        #pragma unroll
        for (int j = 0; j < 8; ++j) pf[j] = f2bf(ev[j] * inv);
        pfrag[hh][ii] = pf;
      }
    }

    // ---- PV: outT[e][i] = hT * p ; A-frags from own hT columns, then barrier, then overwrite x ----
    short8 Ah[NH][2];
    #pragma unroll
    for (int hh = 0; hh < NH; ++hh)
      #pragma unroll
      for (int mtE = 0; mtE < 2; ++mtE)
        Ah[hh][mtE] = *(const short8*)&s_xh[(hh * 32 + mtE * 16 + col) * XSTR + wv * NTOK + quad * 8];
    __syncthreads();   // all waves hold their PV inputs before anyone writes x / pool scratch

    floatx4 po[NH][2][2];
    #pragma unroll
    for (int hh = 0; hh < NH; ++hh)
      #pragma unroll
      for (int mtE = 0; mtE < 2; ++mtE) { po[hh][mtE][0] = fz; po[hh][mtE][1] = fz; }
    #pragma unroll
    for (int hh = 0; hh < NH; ++hh)
      #pragma unroll
      for (int mtE = 0; mtE < 2; ++mtE)
        #pragma unroll
        for (int nt = 0; nt < 2; ++nt)
          po[hh][mtE][nt] = mfma16(Ah[hh][mtE], pfrag[hh][nt], po[hh][mtE][nt]);

    if (L == 0) {
      // x_next[i][e] = elu(outT[e][i])
      #pragma unroll
      for (int hh = 0; hh < NH; ++hh)
        #pragma unroll
        for (int mtE = 0; mtE < 2; ++mtE)
          #pragma unroll
          for (int nt = 0; nt < 2; ++nt)
            #pragma unroll
            for (int r = 0; r < 4; ++r) {
              float v = elu1(po[hh][mtE][nt][r]);
              s_xh[(wv * NTOK + nt * 16 + col) * XSTR + hh * 32 + mtE * 16 + quad * 4 + r] = f2bf(v);
            }
    } else {
      // masked mean pool straight from C-regs
      float alvI0 = s_alive[wv * NTOK + col];
      float alvI1 = s_alive[wv * NTOK + 16 + col];
      float invc = s_inv[wv];
      #pragma unroll
      for (int hh = 0; hh < NH; ++hh)
        #pragma unroll
        for (int mtE = 0; mtE < 2; ++mtE)
          #pragma unroll
          for (int r = 0; r < 4; ++r) {
            float s = elu1(po[hh][mtE][0][r]) * alvI0 + elu1(po[hh][mtE][1][r]) * alvI1;
            s += __shfl_xor(s, 1); s += __shfl_xor(s, 2);
            s += __shfl_xor(s, 4); s += __shfl_xor(s, 8);    // sum 16 cols (all i)
            if (col == 0)
              s_alpha[wv * 128 + hh * 32 + mtE * 16 + quad * 4 + r] = s;  // alpha scratch is free now
          }
      float r0 = s_alpha[wv * 128 + lane];
      float r1 = s_alpha[wv * 128 + 64 + lane];
      out[(size_t)b * EMB + lane]      = r0 * invc;
      out[(size_t)b * EMB + 64 + lane] = r1 * invc;
    }
  }
}

extern "C" void kernel_launch(void* const* d_in, const int* in_sizes, int n_in,
                              void* d_out, int out_size, void* d_ws, size_t ws_size,
                              hipStream_t stream) {
  const float* obs = (const float*)d_in[0];
  const float* Wv  = (const float*)d_in[1];
  const float* bv  = (const float*)d_in[2];
  const float* Wp  = (const float*)d_in[3];
  const float* bp  = (const float*)d_in[4];
  const float* w0  = (const float*)d_in[5];
  const float* as0 = (const float*)d_in[6];
  const float* ad0 = (const float*)d_in[7];
  const float* w1  = (const float*)d_in[8];
  const float* as1 = (const float*)d_in[9];
  const float* ad1 = (const float*)d_in[10];
  float* out = (float*)d_out;

  int Bn = in_sizes[0] / OBSL;       // 4096
  dim3 grid(Bn / 4), block(256);     // 4 items per block (one per wave)
  gnn_fused<<<grid, block, 0, stream>>>(obs, Wv, bv, Wp, bp, w0, as0, ad0, w1, as1, ad1, out);
}

// Round 2
// 139.079 us; speedup vs baseline: 1.0550x; 1.0550x over previous
//
#include <hip/hip_runtime.h>

// GNNCriticEncoder fused kernel v2 (MI355X / gfx950)
// Pre-kernel converts weights fp32->bf16 transposed into d_ws (L2-resident);
// main kernel: 1 wave per item, A-frags straight from global, 3 barriers total.

#define NTOK 32
#define EMB  128
#define OBSL 1056
#define XSTR 136   // s_xh row stride in bf16: 272 B (16B-aligned rows)

typedef __attribute__((ext_vector_type(8))) short  short8;   // 8 x bf16 MFMA A/B frag
typedef __attribute__((ext_vector_type(4))) float  floatx4;  // MFMA C/D frag
typedef __attribute__((ext_vector_type(2))) unsigned uint2v;

__device__ __forceinline__ short f2bf(float f) {             // scalar RNE (prep kernel only)
  union { float f; unsigned u; } v; v.f = f;
  unsigned r = (v.u + 0x7fffu + ((v.u >> 16) & 1u)) >> 16;
  return (short)(unsigned short)r;
}
// HW packed fp32->bf16 (RNE): D[15:0]=cvt(a), D[31:16]=cvt(b)
__device__ __forceinline__ unsigned pk2(float a, float b) {
  unsigned r; asm("v_cvt_pk_bf16_f32 %0, %1, %2" : "=v"(r) : "v"(a), "v"(b)); return r;
}
__device__ __forceinline__ float elu1(float v) { return v > 0.f ? v : __expf(v) - 1.f; }
__device__ __forceinline__ floatx4 mfma16(short8 a, short8 b, floatx4 c) {
  return __builtin_amdgcn_mfma_f32_16x16x32_bf16(a, b, c, 0, 0, 0);
}

// ws layout (bf16): [0,8192) embT[e][k] (k<64: rows<40 Wv, else Wp) | [8192,24576) wT0[e][k] | [24576,40960) wT1[e][k]
__global__ void prep_weights(const float* __restrict__ Wv, const float* __restrict__ Wp,
                             const float* __restrict__ w0, const float* __restrict__ w1,
                             short* __restrict__ ws) {
  int idx = blockIdx.x * 256 + threadIdx.x;          // 160 blocks x 256 = 40960
  if (idx < 8192) {
    int e = idx >> 6, k = idx & 63;
    float v = (k < 40) ? Wv[(size_t)k * EMB + e] : Wp[(size_t)(k - 40) * EMB + e];
    ws[idx] = f2bf(v);
  } else if (idx < 24576) {
    int t = idx - 8192; int e = t >> 7, k = t & 127;
    ws[idx] = f2bf(w0[(size_t)k * EMB + e]);
  } else {
    int t = idx - 24576; int e = t >> 7, k = t & 127;
    ws[idx] = f2bf(w1[(size_t)k * EMB + e]);
  }
}

__global__ __launch_bounds__(256, 4) void gnn_fused(
    const float* __restrict__ obs,
    const float* __restrict__ bv, const float* __restrict__ bp,
    const float* __restrict__ as0, const float* __restrict__ ad0,
    const float* __restrict__ as1, const float* __restrict__ ad1,
    const short* __restrict__ wsb,
    float* __restrict__ out)
{
  __shared__ __align__(16) short s_xh[EMB * XSTR];   // 34816 B: x[token][e] <-> hT[e][token]
  __shared__ float s_pool[4 * EMB];                  // 2048 B: pooled partials per item

  const int tid  = threadIdx.x;
  const int lane = tid & 63;
  const int wv   = tid >> 6;
  const int col  = lane & 15;
  const int quad = lane >> 4;
  const int b    = blockIdx.x * 4 + wv;

  const float* orow = obs + (size_t)b * OBSL;
  short* xbase = &s_xh[(wv * NTOK) * XSTR];
  const short8  z8 = {0,0,0,0,0,0,0,0};
  const floatx4 fz = {0.f,0.f,0.f,0.f};

  // ---------------- P0: alive flags (register-only), zero-pad, obs scatter ----------------
  float flag; float invc;
  {
    float araw = (lane < NTOK) ? orow[1024 + lane] : 0.f;
    bool alv = (lane < NTOK) && (araw >= 0.5f);
    unsigned long long m = __ballot(alv);
    int cnt = __popcll(m);
    flag = alv ? 1.f : 0.f;
    if (cnt == 0) { flag = (lane < NTOK) ? 1.f : 0.f; cnt = NTOK; }
    invc = 1.f / (float)cnt;
  }
  float alv8[8];                                    // alive of keys j = quad*8+jj (PV layout)
  #pragma unroll
  for (int jj = 0; jj < 8; ++jj) alv8[jj] = __shfl(flag, quad * 8 + jj);
  const float alvI0 = __shfl(flag, col);            // alive of token col / 16+col (pool layout)
  const float alvI1 = __shfl(flag, 16 + col);

  #pragma unroll
  for (int it = 0; it < 4; ++it) {                  // zero cols [0,64) of own 32 rows
    int c = it * 64 + lane;
    *(short8*)&xbase[(c >> 3) * XSTR + (c & 7) * 8] = z8;
  }
  #pragma unroll
  for (int it = 0; it < 16; ++it) {                 // coalesced read, bf16 scatter
    int idx = it * 64 + lane;
    float v = orow[idx];
    int r, k;
    if (idx < 640) { r = idx / 40; k = idx % 40; }
    else { int t2 = idx - 640; r = 16 + t2 / 24; k = 40 + t2 % 24; }
    xbase[r * XSTR + k] = f2bf(v);
  }

  // ---------------- P1: embed  D[e][tok] = embT x xin, packed b64 store as x[tok][e] ----------------
  {
    short8 Bxin[2][2];                               // all xin frags before overwriting rows
    #pragma unroll
    for (int nt = 0; nt < 2; ++nt)
      #pragma unroll
      for (int kt = 0; kt < 2; ++kt)
        Bxin[nt][kt] = *(const short8*)&xbase[(nt * 16 + col) * XSTR + kt * 32 + quad * 8];
    const short* embT = wsb;
    #pragma unroll
    for (int mtE = 0; mtE < 8; ++mtE) {
      short8 A0 = *(const short8*)&embT[(mtE * 16 + col) * 64 + quad * 8];
      short8 A1 = *(const short8*)&embT[(mtE * 16 + col) * 64 + 32 + quad * 8];
      float4 bv4 = *(const float4*)&bv[mtE * 16 + quad * 4];
      float4 bp4 = *(const float4*)&bp[mtE * 16 + quad * 4];
      #pragma unroll
      for (int nt = 0; nt < 2; ++nt) {
        floatx4 acc = fz;
        acc = mfma16(A0, Bxin[nt][0], acc);
        acc = mfma16(A1, Bxin[nt][1], acc);
        float4 bb = nt ? bp4 : bv4;
        uint2v u; u.x = pk2(acc[0] + bb.x, acc[1] + bb.y); u.y = pk2(acc[2] + bb.z, acc[3] + bb.w);
        *(uint2v*)&xbase[(nt * 16 + col) * XSTR + mtE * 16 + quad * 4] = u;
      }
    }
  }

  // ---------------- GAT layers ----------------
  for (int L = 0; L < 2; ++L) {
    const short* wT  = wsb + 8192 + L * 16384;
    const float* gas = L ? as1 : as0;
    const float* gad = L ? ad1 : ad0;

    // all x B-frags into regs before hT overwrites other strips
    short8 Bx[4][2];
    #pragma unroll
    for (int kt = 0; kt < 4; ++kt)
      #pragma unroll
      for (int nt = 0; nt < 2; ++nt)
        Bx[kt][nt] = *(const short8*)&xbase[(nt * 16 + col) * XSTR + kt * 32 + quad * 8];
    __syncthreads();                                 // barrier #1: x reads done before hT writes

    // hT[e][tok] = wT x xT, in 2 mt-groups of 4 (register budget)
    float psrc[4][2], pdst[4][2];
    #pragma unroll
    for (int hh = 0; hh < 4; ++hh) { psrc[hh][0]=0.f; psrc[hh][1]=0.f; pdst[hh][0]=0.f; pdst[hh][1]=0.f; }
    #pragma unroll
    for (int g = 0; g < 2; ++g) {
      floatx4 acc[4][2];
      #pragma unroll
      for (int mi = 0; mi < 4; ++mi) { acc[mi][0] = fz; acc[mi][1] = fz; }
      #pragma unroll
      for (int mi = 0; mi < 4; ++mi) {
        const int mt = g * 4 + mi;
        const short* wrow = &wT[(mt * 16 + col) * 128 + quad * 8];
        short8 A0 = *(const short8*)&wrow[0];
        short8 A1 = *(const short8*)&wrow[32];
        short8 A2 = *(const short8*)&wrow[64];
        short8 A3 = *(const short8*)&wrow[96];
        #pragma unroll
        for (int nt = 0; nt < 2; ++nt) {
          acc[mi][nt] = mfma16(A0, Bx[0][nt], acc[mi][nt]);
          acc[mi][nt] = mfma16(A1, Bx[1][nt], acc[mi][nt]);
          acc[mi][nt] = mfma16(A2, Bx[2][nt], acc[mi][nt]);
          acc[mi][nt] = mfma16(A3, Bx[3][nt], acc[mi][nt]);
        }
      }
      #pragma unroll
      for (int mi = 0; mi < 4; ++mi) {
        const int mt = g * 4 + mi;
        const int hh = mt >> 1;
        float4 cs = *(const float4*)&gas[mt * 16 + quad * 4];
        float4 cd = *(const float4*)&gad[mt * 16 + quad * 4];
        #pragma unroll
        for (int nt = 0; nt < 2; ++nt) {
          floatx4 a = acc[mi][nt];
          psrc[hh][nt] += a[0]*cs.x + a[1]*cs.y + a[2]*cs.z + a[3]*cs.w;
          pdst[hh][nt] += a[0]*cd.x + a[1]*cd.y + a[2]*cd.z + a[3]*cd.w;
          unsigned u01 = pk2(a[0], a[1]);
          unsigned u23 = pk2(a[2], a[3]);
          unsigned short* hrow = (unsigned short*)&s_xh[(mt * 16 + quad * 4) * XSTR + wv * NTOK + nt * 16 + col];
          hrow[0]        = (unsigned short)u01;
          hrow[XSTR]     = (unsigned short)(u01 >> 16);
          hrow[2 * XSTR] = (unsigned short)u23;
          hrow[3 * XSTR] = (unsigned short)(u23 >> 16);
        }
      }
    }

    // full per-token alpha in every lane (token = nt*16 + col)
    #pragma unroll
    for (int hh = 0; hh < 4; ++hh)
      #pragma unroll
      for (int nt = 0; nt < 2; ++nt) {
        float vs = psrc[hh][nt]; vs += __shfl_xor(vs, 16); vs += __shfl_xor(vs, 32); psrc[hh][nt] = vs;
        float vd = pdst[hh][nt]; vd += __shfl_xor(vd, 16); vd += __shfl_xor(vd, 32); pdst[hh][nt] = vd;
      }

    // softmax in PV B-frag layout: lane owns (i = ii*16+col, j = quad*8+jj)
    short8 pf[4][2];
    #pragma unroll
    for (int hh = 0; hh < 4; ++hh) {
      float vsel = (quad >> 1) ? pdst[hh][1] : pdst[hh][0];
      float ad8[8];
      #pragma unroll
      for (int jj = 0; jj < 8; ++jj)
        ad8[jj] = __shfl(vsel, ((quad >> 1) << 5) + ((quad & 1) << 3) + jj);
      #pragma unroll
      for (int ii = 0; ii < 2; ++ii) {
        float ai = psrc[hh][ii];
        float ev[8]; float mx = -3e38f;
        #pragma unroll
        for (int jj = 0; jj < 8; ++jj) {
          float e = ai + ad8[jj];
          e = e > 0.f ? e : 0.2f * e;
          e = (alv8[jj] >= 0.5f) ? e : -1e30f;
          ev[jj] = e; mx = fmaxf(mx, e);
        }
        mx = fmaxf(mx, __shfl_xor(mx, 16));
        mx = fmaxf(mx, __shfl_xor(mx, 32));
        float sum = 0.f;
        #pragma unroll
        for (int jj = 0; jj < 8; ++jj) { float p = __expf(ev[jj] - mx); ev[jj] = p; sum += p; }
        sum += __shfl_xor(sum, 16);
        sum += __shfl_xor(sum, 32);
        float inv = 1.f / sum;
        union { unsigned u4[4]; short8 s; } pu;
        #pragma unroll
        for (int p = 0; p < 4; ++p) pu.u4[p] = pk2(ev[2*p] * inv, ev[2*p+1] * inv);
        pf[hh][ii] = pu.s;
      }
    }

    // PV A-frags (hT own column strip), then single barrier, then MFMA + direct epilogue
    short8 Ah[4][2];
    #pragma unroll
    for (int hh = 0; hh < 4; ++hh)
      #pragma unroll
      for (int mtE = 0; mtE < 2; ++mtE)
        Ah[hh][mtE] = *(const short8*)&s_xh[(hh * 32 + mtE * 16 + col) * XSTR + wv * NTOK + quad * 8];
    if (L == 0) __syncthreads();                     // barrier #2: hT reads done before x_next writes

    #pragma unroll
    for (int hh = 0; hh < 4; ++hh)
      #pragma unroll
      for (int mtE = 0; mtE < 2; ++mtE) {
        floatx4 po[2];
        #pragma unroll
        for (int nt = 0; nt < 2; ++nt) {
          po[nt] = mfma16(Ah[hh][mtE], pf[hh][nt], fz);
        }
        if (L == 0) {
          #pragma unroll
          for (int nt = 0; nt < 2; ++nt) {
            uint2v u;
            u.x = pk2(elu1(po[nt][0]), elu1(po[nt][1]));
            u.y = pk2(elu1(po[nt][2]), elu1(po[nt][3]));
            *(uint2v*)&xbase[(nt * 16 + col) * XSTR + hh * 32 + mtE * 16 + quad * 4] = u;
          }
        } else {
          #pragma unroll
          for (int r = 0; r < 4; ++r) {
            float s = elu1(po[0][r]) * alvI0 + elu1(po[1][r]) * alvI1;
            s += __shfl_xor(s, 1); s += __shfl_xor(s, 2);
            s += __shfl_xor(s, 4); s += __shfl_xor(s, 8);
            if (col == 0) s_pool[wv * EMB + hh * 32 + mtE * 16 + quad * 4 + r] = s;
          }
        }
      }
  }

  // ---------------- pooled output (same-wave LDS, no barrier) ----------------
  float r0 = s_pool[wv * EMB + lane];
  float r1 = s_pool[wv * EMB + 64 + lane];
  out[(size_t)b * EMB + lane]      = r0 * invc;
  out[(size_t)b * EMB + 64 + lane] = r1 * invc;
}

extern "C" void kernel_launch(void* const* d_in, const int* in_sizes, int n_in,
                              void* d_out, int out_size, void* d_ws, size_t ws_size,
                              hipStream_t stream) {
  const float* obs = (const float*)d_in[0];
  const float* Wv  = (const float*)d_in[1];
  const float* bv  = (const float*)d_in[2];
  const float* Wp  = (const float*)d_in[3];
  const float* bp  = (const float*)d_in[4];
  const float* w0  = (const float*)d_in[5];
  const float* as0 = (const float*)d_in[6];
  const float* ad0 = (const float*)d_in[7];
  const float* w1  = (const float*)d_in[8];
  const float* as1 = (const float*)d_in[9];
  const float* ad1 = (const float*)d_in[10];
  float* out = (float*)d_out;
  short* wsb = (short*)d_ws;                      // needs 80 KiB

  int Bn = in_sizes[0] / OBSL;                    // 4096
  prep_weights<<<160, 256, 0, stream>>>(Wv, Wp, w0, w1, wsb);
  gnn_fused<<<Bn / 4, 256, 0, stream>>>(obs, bv, bp, as0, ad0, as1, ad1, wsb, out);
}